// Round 16
// baseline (398.913 us; speedup 1.0000x reference)
//
#include <hip/hip_runtime.h>
#include <hip/hip_bf16.h>
#include <stdint.h>

#define N_  6144
#define T_  3072
#define D_  128
#define H_  4
#define HD_ 512

typedef float f32x4 __attribute__((ext_vector_type(4)));
typedef _Float16 f16x8 __attribute__((ext_vector_type(8)));
typedef _Float16 h16x4 __attribute__((ext_vector_type(4)));

#define GLL16(g, s) __builtin_amdgcn_global_load_lds( \
    (const __attribute__((address_space(1))) unsigned int*)(g), \
    (__attribute__((address_space(3))) unsigned int*)(s), 16, 0, 0)

static __device__ __forceinline__ short f2h(float f) {
  union { _Float16 h; short s; } u;
  u.h = (_Float16)f;
  return u.s;
}
static __device__ __forceinline__ unsigned pk2(float f) {
  union { _Float16 h[2]; unsigned u; } t;
  t.h[0] = (_Float16)f; t.h[1] = t.h[0];
  return t.u;
}
static __device__ __forceinline__ unsigned pkmul(unsigned a, unsigned b) {
  unsigned r;
  asm("v_pk_mul_f16 %0, %1, %2" : "=v"(r) : "v"(a), "v"(b));
  return r;
}
static __device__ __forceinline__ unsigned pkmax(unsigned a, unsigned b) {
  unsigned r;
  asm("v_pk_max_f16 %0, %1, %2" : "=v"(r) : "v"(a), "v"(b));
  return r;
}

// ---------------- adj + t_adj -> bitmasks, 8 words/wave-iter ----------------
__global__ __launch_bounds__(256) void bits8_kernel(const int* __restrict__ a0,
                                                    const int* __restrict__ a1,
                                                    unsigned long long* __restrict__ b0,
                                                    unsigned long long* __restrict__ b1,
                                                    int nw0, int nw1) {
  int lane = threadIdx.x & 63;
  int gw = (blockIdx.x * blockDim.x + threadIdx.x) >> 6;
  int nw = (gridDim.x * blockDim.x) >> 6;
  int total8 = (nw0 + nw1) >> 3;
  for (int g = gw; g < total8; g += nw) {
    int w = g * 8;
    const int* src; unsigned long long* dst; long wi;
    if (w < nw0) { src = a0; dst = b0; wi = w; }
    else         { src = a1; dst = b1; wi = w - nw0; }
    int v[8];
#pragma unroll
    for (int j = 0; j < 8; ++j) v[j] = src[(wi + j) * 64 + lane];
    unsigned long long bb[8];
#pragma unroll
    for (int j = 0; j < 8; ++j) bb[j] = __ballot(v[j] != 0);
    if (lane == 0) {
      ulonglong2 s01 = {bb[0], bb[1]}, s23 = {bb[2], bb[3]};
      ulonglong2 s45 = {bb[4], bb[5]}, s67 = {bb[6], bb[7]};
      *(ulonglong2*)(dst + wi + 0) = s01;
      *(ulonglong2*)(dst + wi + 2) = s23;
      *(ulonglong2*)(dst + wi + 4) = s45;
      *(ulonglong2*)(dst + wi + 6) = s67;
    }
  }
}

// ---------------- x + t_x fp32 -> fp16, one launch ----------------
__global__ __launch_bounds__(256) void cvt2_kernel(const float* __restrict__ in0,
                                                   short* __restrict__ out0,
                                                   const float* __restrict__ in1,
                                                   short* __restrict__ out1,
                                                   int c0, int c1) {
  int i = blockIdx.x * blockDim.x + threadIdx.x;
  const float* in; short* out; long ii;
  if (i < c0) { in = in0; out = out0; ii = i; }
  else if (i < c0 + c1) { in = in1; out = out1; ii = i - c0; }
  else return;
  float4 v = *(const float4*)(in + ii * 4);
  short4 o;
  o.x = f2h(v.x); o.y = f2h(v.y); o.z = f2h(v.z); o.w = f2h(v.w);
  *(short4*)(out + ii * 4) = o;
}

// ---------------- fp32 [R][C] -> fp16 [C][R], two jobs per launch ----------------
__global__ __launch_bounds__(256) void tcvt2_kernel(const float* __restrict__ in0,
                                                    short* __restrict__ out0,
                                                    const float* __restrict__ in1,
                                                    short* __restrict__ out1,
                                                    int R, int C, long sIn, long sOut,
                                                    int zsplit) {
  __shared__ float t[32][33];
  const float* in; short* out;
  int z = blockIdx.z;
  if (z < zsplit) { in = in0 + (long)z * sIn; out = out0 + (long)z * sOut; }
  else            { in = in1 + (long)(z - zsplit) * sIn; out = out1 + (long)(z - zsplit) * sOut; }
  int c0 = blockIdx.x * 32, r0 = blockIdx.y * 32;
  int tx = threadIdx.x, ty = threadIdx.y;
#pragma unroll
  for (int i = 0; i < 4; ++i)
    t[ty + 8 * i][tx] = in[(long)(r0 + ty + 8 * i) * C + c0 + tx];
  __syncthreads();
#pragma unroll
  for (int i = 0; i < 4; ++i)
    out[(long)(c0 + ty + 8 * i) * R + r0 + tx] = f2h(t[tx][ty + 8 * i]);
}

// ---------------- node factors, G+T merged ----------------
__global__ __launch_bounds__(256) void fvec2_kernel(const float* __restrict__ x0,
                                                    const float* __restrict__ W0,
                                                    const float* __restrict__ as0,
                                                    const float* __restrict__ ad0,
                                                    float* __restrict__ ea0, float* __restrict__ ec0,
                                                    short* __restrict__ eb0, short* __restrict__ ed0,
                                                    int n0, int xsplit,
                                                    const float* __restrict__ x1,
                                                    const float* __restrict__ W1,
                                                    const float* __restrict__ as1,
                                                    const float* __restrict__ ad1,
                                                    float* __restrict__ ea1, float* __restrict__ ec1,
                                                    short* __restrict__ eb1, short* __restrict__ ed1,
                                                    int n1) {
  const float *x, *W, *a_s, *a_d;
  float *ea, *ec; short *ebh, *edh; int n; long bx;
  if ((int)blockIdx.x < xsplit) { x=x0; W=W0; a_s=as0; a_d=ad0; ea=ea0; ec=ec0; ebh=eb0; edh=ed0; n=n0; bx=blockIdx.x; }
  else { x=x1; W=W1; a_s=as1; a_d=ad1; ea=ea1; ec=ec1; ebh=eb1; edh=ed1; n=n1; bx=blockIdx.x - xsplit; }
  __shared__ float usl[128], udl[128], asl[128], adl[128];
  long idx = bx * 256 + threadIdx.x;
  int h = (int)(idx / n), i = (int)(idx % n);
  int tid = threadIdx.x;
  if (tid < 128) {
    asl[tid] = a_s[h * D_ + tid];
    adl[tid] = a_d[h * D_ + tid];
  }
  __syncthreads();
  {
    int d = tid & 127;
    const float* wr = W + ((long)h * D_ + d) * D_;
    const float* av = (tid < 128) ? asl : adl;
    float s = 0.f;
#pragma unroll 8
    for (int e = 0; e < D_; ++e) s += wr[e] * av[e];
    if (tid < 128) usl[d] = s; else udl[d] = s;
  }
  __syncthreads();
  const float4* xr = (const float4*)(x + (long)i * D_);
  float s = 0.f, t = 0.f;
#pragma unroll 8
  for (int e4 = 0; e4 < 32; ++e4) {
    float4 xv = xr[e4];
    s += xv.x * usl[4 * e4] + xv.y * usl[4 * e4 + 1] + xv.z * usl[4 * e4 + 2] + xv.w * usl[4 * e4 + 3];
    t += xv.x * udl[4 * e4] + xv.y * udl[4 * e4 + 1] + xv.z * udl[4 * e4 + 2] + xv.w * udl[4 * e4 + 3];
  }
  const float L2E = 1.4426950408889634f;
  float fs = s * L2E, fd = t * L2E;
  ea[idx]  = exp2f(fs);
  ec[idx]  = exp2f(0.2f * fs);
  ebh[idx] = f2h(exp2f(fd));
  edh[idx] = f2h(exp2f(0.2f * fd));
}

// ---------------- GEMM core (3-buffer depth-2 GLL pipeline) ----
#define GEMM_BODY(A, BT, K, lda, ldb, outF, outB, ldo, epi, sOutOff)            \
  {                                                                             \
    __shared__ __align__(16) short bs[3][4096];                                 \
    int tid = threadIdx.x, w = tid >> 6, l = tid & 63, lm = l & 15, lg = l >> 4;\
    int row0 = blockIdx.x * 64 + w * 16;                                        \
    int col0 = blockIdx.y * 128;                                                \
    const short* arow = (A) + (long)(row0 + lm) * (lda) + 8 * lg;               \
    const short* bsrc = (BT) + (long)(col0 + 16 * (2 * w) + lm) * (ldb) + 8 * lg;\
    f32x4 acc[8] = {};                                                          \
    int nt = (K) / 32;                                                          \
    f16x8 af = *(const f16x8*)(arow);                                           \
    GLL16(bsrc, &bs[0][(2 * w) * 512]);                                         \
    GLL16(bsrc + 16 * (ldb), &bs[0][(2 * w + 1) * 512]);                        \
    GLL16(bsrc + 32, &bs[1][(2 * w) * 512]);                                    \
    GLL16(bsrc + 32 + 16 * (ldb), &bs[1][(2 * w + 1) * 512]);                   \
    for (int kt = 0; kt < nt; ++kt) {                                           \
      int cur = kt % 3;                                                         \
      int kb = (kt + 1 < nt ? kt + 1 : kt) * 32;                                \
      f16x8 an = *(const f16x8*)(arow + kb);                                    \
      asm volatile("s_waitcnt vmcnt(3)" ::: "memory");                          \
      __builtin_amdgcn_sched_barrier(0);                                        \
      __builtin_amdgcn_s_barrier();                                             \
      __builtin_amdgcn_sched_barrier(0);                                        \
      _Pragma("unroll")                                                         \
      for (int f = 0; f < 8; ++f) {                                             \
        f16x8 bf = *(const f16x8*)(&bs[cur][f * 512 + l * 8]);                  \
        acc[f] = __builtin_amdgcn_mfma_f32_16x16x32_f16(af, bf, acc[f], 0, 0, 0);\
      }                                                                         \
      {                                                                         \
        int kg = (kt + 2 < nt ? kt + 2 : nt - 1) * 32;                          \
        int tb = (kt + 2) % 3;                                                  \
        GLL16(bsrc + kg, &bs[tb][(2 * w) * 512]);                               \
        GLL16(bsrc + kg + 16 * (ldb), &bs[tb][(2 * w + 1) * 512]);              \
      }                                                                         \
      __builtin_amdgcn_sched_barrier(0);                                        \
      af = an;                                                                  \
    }                                                                           \
    _Pragma("unroll")                                                           \
    for (int f = 0; f < 8; ++f) {                                               \
      int col = col0 + 16 * f + lm;                                             \
      _Pragma("unroll")                                                         \
      for (int r = 0; r < 4; ++r) {                                             \
        int row = row0 + 4 * lg + r;                                            \
        if ((epi) == 0) (outB)[(sOutOff) + (long)row * (ldo) + col] = f2h(acc[f][r]); \
        else            (outF)[(sOutOff) + (long)row * (ldo) + col] = acc[f][r];\
      }                                                                         \
    }                                                                           \
  }

__global__ __launch_bounds__(256) void gemm_kernel(const short* __restrict__ A,
                                                   const short* __restrict__ BT,
                                                   int K, int lda, int ldb,
                                                   float* __restrict__ outF, short* __restrict__ outB,
                                                   int ldo, int epi,
                                                   long sA, long sBT, long sOut) {
  int bz = blockIdx.z;
  const short* Ab = A + bz * sA;
  const short* Bb = BT + bz * sBT;
  long oOff = bz * sOut;
  GEMM_BODY(Ab, Bb, K, lda, ldb, outF, outB, ldo, epi, oOff)
}

__global__ __launch_bounds__(256) void gemm2_kernel(const short* __restrict__ A0,
                                                    const short* __restrict__ BT0,
                                                    float* __restrict__ oF0, short* __restrict__ oB0,
                                                    int ldo0, long sOut0, int xlim0, int ylim0,
                                                    const short* __restrict__ A1,
                                                    const short* __restrict__ BT1,
                                                    float* __restrict__ oF1, short* __restrict__ oB1,
                                                    int ldo1, long sOut1, int xlim1, int ylim1,
                                                    int K, int lda, int ldb, int epi,
                                                    long sA, long sBT, int zsplit) {
  int z = blockIdx.z;
  const short *A, *BT; float* outF; short* outB; int ldo; long sOut; int bz;
  if (z < zsplit) {
    if ((int)blockIdx.x >= xlim0 || (int)blockIdx.y >= ylim0) return;
    A = A0; BT = BT0; outF = oF0; outB = oB0; ldo = ldo0; sOut = sOut0; bz = z;
  } else {
    if ((int)blockIdx.x >= xlim1 || (int)blockIdx.y >= ylim1) return;
    A = A1; BT = BT1; outF = oF1; outB = oB1; ldo = ldo1; sOut = sOut1; bz = z - zsplit;
  }
  const short* Ab = A + bz * sA;
  const short* Bb = BT + bz * sBT;
  long oOff = bz * sOut;
  GEMM_BODY(Ab, Bb, K, lda, ldb, outF, outB, ldo, epi, oOff)
}

// ---------------- reduce fc partials: sum + bias + relu, fp16 transposed out ----
__global__ __launch_bounds__(256) void reduce_kernel(const float* __restrict__ P,
                                                     int S, long sP,
                                                     const float* __restrict__ bias,
                                                     short* __restrict__ outB,
                                                     int ldo) {
  __shared__ short sm[128][68];
  int tid = threadIdx.x;
  int r0 = blockIdx.x * 64;
#pragma unroll
  for (int k = 0; k < 8; ++k) {
    int e = tid * 4 + k * 1024;
    int row = e >> 7, col = e & 127;
    f32x4 v = {};
    for (int s = 0; s < S; ++s)
      v += *(const f32x4*)(P + (long)s * sP + (long)(r0 + row) * 128 + col);
    const float4 bv = *(const float4*)(bias + col);
    v[0] += bv.x; v[1] += bv.y; v[2] += bv.z; v[3] += bv.w;
#pragma unroll
    for (int q = 0; q < 4; ++q) v[q] = v[q] > 0.f ? v[q] : 0.f;
    sm[col + 0][row] = f2h(v[0]);
    sm[col + 1][row] = f2h(v[1]);
    sm[col + 2][row] = f2h(v[2]);
    sm[col + 3][row] = f2h(v[3]);
  }
  __syncthreads();
  int d = tid >> 1, seg = tid & 1;
  short* dst = outB + (long)d * ldo + r0 + seg * 32;
#pragma unroll
  for (int q = 0; q < 8; ++q) {
    short4 o;
    o.x = sm[d][seg * 32 + 4 * q + 0];
    o.y = sm[d][seg * 32 + 4 * q + 1];
    o.z = sm[d][seg * 32 + 4 * q + 2];
    o.w = sm[d][seg * 32 + 4 * q + 3];
    *(short4*)(dst + 4 * q) = o;
  }
}

// ---------------- merged masked-softmax attention (G+T), 2 LDS buffers ----
__global__ __launch_bounds__(256) void attn2_kernel(const short* __restrict__ WhT0,
                                                    const unsigned char* __restrict__ bits0,
                                                    const float* __restrict__ ea0A,
                                                    const float* __restrict__ ec0A,
                                                    const short* __restrict__ eb0A,
                                                    const short* __restrict__ ed0A,
                                                    _Float16* __restrict__ pacc0,
                                                    float* __restrict__ pz0,
                                                    int n0, int S0, int RB0,
                                                    const short* __restrict__ WhT1,
                                                    const unsigned char* __restrict__ bits1,
                                                    const float* __restrict__ ea1A,
                                                    const float* __restrict__ ec1A,
                                                    const short* __restrict__ eb1A,
                                                    const short* __restrict__ ed1A,
                                                    _Float16* __restrict__ pacc1,
                                                    float* __restrict__ pz1,
                                                    int n1, int S1, int RB1) {
  int z = blockIdx.z;
  const short* WhT; const unsigned char* bits;
  const float *eaA, *ecA; const short *ebA, *edA;
  _Float16* pacc; float* pz; int n, S, RB, sp;
  if (z < S0) {
    WhT = WhT0; bits = bits0; eaA = ea0A; ecA = ec0A; ebA = eb0A; edA = ed0A;
    pacc = pacc0; pz = pz0; n = n0; S = S0; RB = RB0; sp = z;
  } else {
    if ((int)blockIdx.x >= RB1) return;
    WhT = WhT1; bits = bits1; eaA = ea1A; ecA = ec1A; ebA = eb1A; edA = ed1A;
    pacc = pacc1; pz = pz1; n = n1; S = S1; RB = RB1; sp = z - S0;
  }
  int h = blockIdx.y;
  int klen = n / S, k0 = sp * klen;
  const short* whT = WhT + (long)h * D_ * n;
  const short* ebp = ebA + (long)h * n;
  const short* edp = edA + (long)h * n;
  __shared__ __align__(16) short bs[2][4096];
  int tid = threadIdx.x, w = tid >> 6, l = tid & 63, lm = l & 15, lg = l >> 4;
  int i0 = blockIdx.x * 128;
  int r0 = i0 + 32 * w + lm;
  int r1 = r0 + 16;
  unsigned ea0p = pk2(eaA[(long)h * n + r0]), ea1p = pk2(eaA[(long)h * n + r1]);
  unsigned ec0p = pk2(ecA[(long)h * n + r0]), ec1p = pk2(ecA[(long)h * n + r1]);
  const unsigned char* brow0 = bits + (long)r0 * (n >> 3);
  const unsigned char* brow1 = bits + (long)r1 * (n >> 3);
  const short* bsrc = whT + (long)(16 * (2 * w) + lm) * n + 8 * lg + k0;
  f32x4 acc0[8] = {}, acc1[8] = {};
  f32x4 az0 = {}, az1 = {};
  f16x8 ones;
#pragma unroll
  for (int j = 0; j < 8; ++j) ones[j] = (_Float16)1.0f;
  int nt = klen / 32;
  unsigned ebR[4], edR[4], ebS[4], edS[4];
  unsigned m0A, m1A, m0B, m1B;
  *(uint4*)(ebR) = *(const uint4*)(ebp + k0 + 8 * lg);
  *(uint4*)(edR) = *(const uint4*)(edp + k0 + 8 * lg);
  m0A = (*(const unsigned*)(brow0 + (k0 >> 3))) >> (8 * lg);
  m1A = (*(const unsigned*)(brow1 + (k0 >> 3))) >> (8 * lg);
  GLL16(bsrc, &bs[0][(2 * w) * 512]);
  GLL16(bsrc + 16 * n, &bs[0][(2 * w + 1) * 512]);

#define ATTN_STEP(KT, EBC, EDC, M0C, M1C, EBN, EDN, M0N, M1N)                   \
  {                                                                             \
    int cur = (KT) & 1, nxt = cur ^ 1;                                          \
    int kb = ((KT) + 1 < nt ? (KT) + 1 : (KT)) * 32;                            \
    *(uint4*)(EBN) = *(const uint4*)(ebp + k0 + kb + 8 * lg);                   \
    *(uint4*)(EDN) = *(const uint4*)(edp + k0 + kb + 8 * lg);                   \
    M0N = (*(const unsigned*)(brow0 + ((k0 + kb) >> 3))) >> (8 * lg);           \
    M1N = (*(const unsigned*)(brow1 + ((k0 + kb) >> 3))) >> (8 * lg);           \
    union { f16x8 v; unsigned u[4]; } af0, af1;                                 \
    _Pragma("unroll")                                                           \
    for (int jj = 0; jj < 4; ++jj) {                                            \
      unsigned pm0 = pkmax(pkmul(ea0p, EBC[jj]), pkmul(ec0p, EDC[jj]));         \
      unsigned pm1 = pkmax(pkmul(ea1p, EBC[jj]), pkmul(ec1p, EDC[jj]));         \
      int ta = ((int)(M0C << (31 - 2 * jj))) >> 31;                             \
      int tb = ((int)(M0C << (30 - 2 * jj))) >> 31;                             \
      af0.u[jj] = pm0 & __builtin_amdgcn_perm((unsigned)tb, (unsigned)ta, 0x07060302u); \
      ta = ((int)(M1C << (31 - 2 * jj))) >> 31;                                 \
      tb = ((int)(M1C << (30 - 2 * jj))) >> 31;                                 \
      af1.u[jj] = pm1 & __builtin_amdgcn_perm((unsigned)tb, (unsigned)ta, 0x07060302u); \
    }                                                                           \
    asm volatile("s_waitcnt vmcnt(6)" ::: "memory");                            \
    __builtin_amdgcn_sched_barrier(0);                                          \
    __builtin_amdgcn_s_barrier();                                               \
    __builtin_amdgcn_sched_barrier(0);                                          \
    _Pragma("unroll")                                                           \
    for (int f = 0; f < 8; ++f) {                                               \
      f16x8 bf = *(const f16x8*)(&bs[cur][f * 512 + l * 8]);                    \
      acc0[f] = __builtin_amdgcn_mfma_f32_16x16x32_f16(af0.v, bf, acc0[f], 0, 0, 0); \
      acc1[f] = __builtin_amdgcn_mfma_f32_16x16x32_f16(af1.v, bf, acc1[f], 0, 0, 0); \
    }                                                                           \
    az0 = __builtin_amdgcn_mfma_f32_16x16x32_f16(af0.v, ones, az0, 0, 0, 0);    \
    az1 = __builtin_amdgcn_mfma_f32_16x16x32_f16(af1.v, ones, az1, 0, 0, 0);    \
    if ((KT) + 1 < nt) {                                                        \
      GLL16(bsrc + kb, &bs[nxt][(2 * w) * 512]);                                \
      GLL16(bsrc + kb + 16 * n, &bs[nxt][(2 * w + 1) * 512]);                   \
    }                                                                           \
    __builtin_amdgcn_sched_barrier(0);                                          \
  }

  for (int kt = 0; kt < nt; kt += 2) {
    ATTN_STEP(kt,     ebR, edR, m0A, m1A, ebS, edS, m0B, m1B);
    ATTN_STEP(kt + 1, ebS, edS, m0B, m1B, ebR, edR, m0A, m1A);
  }
#undef ATTN_STEP

  long base = (long)(h * RB + blockIdx.x) * S + sp;
  if (lm == 0) {
#pragma unroll
    for (int r = 0; r < 4; ++r) {
      pz[base * 128 + 32 * w + 4 * lg + r] = az0[r];
      pz[base * 128 + 32 * w + 16 + 4 * lg + r] = az1[r];
    }
  }
  long pb = base * 16384;
#pragma unroll
  for (int f = 0; f < 8; ++f)
#pragma unroll
    for (int r = 0; r < 4; ++r) {
      pacc[pb + (long)(32 * w + 4 * lg + r) * 128 + 16 * f + lm] = (_Float16)acc0[f][r];
      pacc[pb + (long)(32 * w + 16 + 4 * lg + r) * 128 + 16 * f + lm] = (_Float16)acc1[f][r];
    }
}

// ---------------- merged combine (G+T): /Z, elu, write fp16 head-concat ----
__global__ __launch_bounds__(256) void combine2_kernel(const _Float16* __restrict__ pacc0,
                                                       const float* __restrict__ pz0,
                                                       short* __restrict__ hcat0,
                                                       int S0, int RB0,
                                                       const _Float16* __restrict__ pacc1,
                                                       const float* __restrict__ pz1,
                                                       short* __restrict__ hcat1,
                                                       int S1) {
  const _Float16* pacc; const float* pz; short* hcat; int S, RB, rb;
  if ((int)blockIdx.x < RB0) { pacc = pacc0; pz = pz0; hcat = hcat0; S = S0; RB = RB0; rb = blockIdx.x; }
  else { pacc = pacc1; pz = pz1; hcat = hcat1; S = S1; RB = gridDim.x - RB0; rb = blockIdx.x - RB0; }
  int h = blockIdx.y;
  long base = (long)(h * RB + rb) * S;
  __shared__ float zl[128];
  int tid = threadIdx.x;
  if (tid < 128) {
    float zv = 0.f;
    for (int s = 0; s < S; ++s) zv += pz[(base + s) * 128 + tid];
    zl[tid] = 1.f / zv;
  }
  __syncthreads();
  int i0 = rb * 128;
#pragma unroll
  for (int k = 0; k < 16; ++k) {
    int e = tid * 4 + k * 1024;
    int row = e >> 7, col = e & 127;
    f32x4 v = {};
    for (int s = 0; s < S; ++s) {
      h16x4 hv = *(const h16x4*)(pacc + (base + s) * 16384 + e);
      v[0] += (float)hv[0]; v[1] += (float)hv[1];
      v[2] += (float)hv[2]; v[3] += (float)hv[3];
    }
    float iz = zl[row];
    short4 o;
    float t;
    t = v[0] * iz; o.x = f2h(t > 0.f ? t : __expf(t) - 1.f);
    t = v[1] * iz; o.y = f2h(t > 0.f ? t : __expf(t) - 1.f);
    t = v[2] * iz; o.z = f2h(t > 0.f ? t : __expf(t) - 1.f);
    t = v[3] * iz; o.w = f2h(t > 0.f ? t : __expf(t) - 1.f);
    *(short4*)(hcat + (long)(i0 + row) * HD_ + h * D_ + col) = o;
  }
}

// ---------------- gated fusion + final GEMM + relu ----
__global__ __launch_bounds__(256) void fusion_kernel(const float* __restrict__ fcPg,
                                                     int Sf, long sPg,
                                                     const float* __restrict__ fcg_b,
                                                     const float* __restrict__ ctextP,
                                                     int Sc, long sCt,
                                                     const short* __restrict__ fusT,
                                                     const float* __restrict__ fus_b,
                                                     float* __restrict__ out) {
  __shared__ __align__(16) short als[64 * 136];
  int tid = threadIdx.x;
  int r0 = blockIdx.x * 64;
#pragma unroll
  for (int it = 0; it < 8; ++it) {
    int e = it * 1024 + tid * 4;
    int r = e >> 7, c = e & 127;
    f32x4 cv = {};
    for (int s = 0; s < Sf; ++s)
      cv += *(const f32x4*)(fcPg + (long)s * sPg + (long)(r0 + r) * D_ + c);
    const float4 bv = *(const float4*)(fcg_b + c);
    cv[0] += bv.x; cv[1] += bv.y; cv[2] += bv.z; cv[3] += bv.w;
#pragma unroll
    for (int q = 0; q < 4; ++q) cv[q] = cv[q] > 0.f ? cv[q] : 0.f;
    f32x4 tv = {};
    for (int s = 0; s < Sc; ++s)
      tv += *(const f32x4*)(ctextP + (long)s * sCt + (long)(r0 + r) * D_ + c);
    short4 o;
    {
      float s0 = cv[0] + tv[0]; float z = 1.f / (1.f + __expf(-s0)); o.x = f2h(tv[0] + z * (cv[0] - tv[0]));
      s0 = cv[1] + tv[1]; z = 1.f / (1.f + __expf(-s0)); o.y = f2h(tv[1] + z * (cv[1] - tv[1]));
      s0 = cv[2] + tv[2]; z = 1.f / (1.f + __expf(-s0)); o.z = f2h(tv[2] + z * (cv[2] - tv[2]));
      s0 = cv[3] + tv[3]; z = 1.f / (1.f + __expf(-s0)); o.w = f2h(tv[3] + z * (cv[3] - tv[3]));
    }
    *(short4*)(als + (long)r * 136 + c) = o;
  }
  __syncthreads();
  int w = tid >> 6, l = tid & 63, lm = l & 15, lg = l >> 4;
  f32x4 acc[8] = {};
#pragma unroll
  for (int kt = 0; kt < 4; ++kt) {
    int kb = kt * 32;
    f16x8 af = *(const f16x8*)(als + (16 * w + lm) * 136 + kb + 8 * lg);
#pragma unroll
    for (int f = 0; f < 8; ++f) {
      f16x8 bf = *(const f16x8*)(fusT + (long)(16 * f + lm) * D_ + kb + 8 * lg);
      acc[f] = __builtin_amdgcn_mfma_f32_16x16x32_f16(af, bf, acc[f], 0, 0, 0);
    }
  }
#pragma unroll
  for (int f = 0; f < 8; ++f) {
    int col = 16 * f + lm;
#pragma unroll
    for (int r = 0; r < 4; ++r) {
      float v = acc[f][r] + fus_b[col];
      v = v > 0.f ? v : 0.f;
      out[(long)(r0 + 16 * w + 4 * lg + r) * D_ + col] = v;
    }
  }
}

extern "C" void kernel_launch(void* const* d_in, const int* in_sizes, int n_in,
                              void* d_out, int out_size, void* d_ws, size_t ws_size,
                              hipStream_t stream) {
  (void)in_sizes; (void)n_in; (void)out_size;
  const float* x      = (const float*)d_in[0];
  const int*   adj    = (const int*)d_in[1];
  const float* t_x    = (const float*)d_in[2];
  const int*   t_adj  = (const int*)d_in[3];
  const float* tfidf  = (const float*)d_in[4];
  const float* Wg     = (const float*)d_in[5];
  const float* ag_src = (const float*)d_in[6];
  const float* ag_dst = (const float*)d_in[7];
  const float* fcg_W  = (const float*)d_in[8];
  const float* fcg_b  = (const float*)d_in[9];
  const float* Wt     = (const float*)d_in[10];
  const float* at_src = (const float*)d_in[11];
  const float* at_dst = (const float*)d_in[12];
  const float* fct_W  = (const float*)d_in[13];
  const float* fct_b  = (const float*)d_in[14];
  const float* fus_W  = (const float*)d_in[15];
  const float* fus_b  = (const float*)d_in[16];
  float* out = (float*)d_out;

  char* ws = (char*)d_ws;
  size_t off = 0;
  auto alloc = [&](size_t bytes) -> char* {
    char* p = ws + off;
    off = (off + bytes + 255) & ~(size_t)255;
    return p;
  };
  unsigned long long* bitsG = (unsigned long long*)alloc((size_t)N_ * N_ / 8);
  unsigned long long* bitsT = (unsigned long long*)alloc((size_t)T_ * T_ / 8);
  short* xb     = (short*)alloc((size_t)N_ * D_ * 2);
  short* txb    = (short*)alloc((size_t)T_ * D_ * 2);
  short* WgT    = (short*)alloc((size_t)H_ * D_ * D_ * 2);
  short* WtT    = (short*)alloc((size_t)H_ * D_ * D_ * 2);
  short* fcgT   = (short*)alloc((size_t)HD_ * D_ * 2);
  short* fctT   = (short*)alloc((size_t)HD_ * D_ * 2);
  short* fusT   = (short*)alloc((size_t)D_ * D_ * 2);
  short* tfidfT = (short*)alloc((size_t)N_ * T_ * 2);
  short* WhTg   = (short*)alloc((size_t)H_ * D_ * N_ * 2);
  short* WhTt   = (short*)alloc((size_t)H_ * D_ * T_ * 2);
  float* eaG  = (float*)alloc((size_t)H_ * N_ * 4);
  float* ecG  = (float*)alloc((size_t)H_ * N_ * 4);
  short* ebG  = (short*)alloc((size_t)H_ * N_ * 2);
  short* edG  = (short*)alloc((size_t)H_ * N_ * 2);
  float* eaT  = (float*)alloc((size_t)H_ * T_ * 4);
  float* ecT  = (float*)alloc((size_t)H_ * T_ * 4);
  short* ebT  = (short*)alloc((size_t)H_ * T_ * 2);
  short* edT  = (short*)alloc((size_t)H_ * T_ * 2);
  short* hcatG = (short*)alloc((size_t)N_ * HD_ * 2);
  short* hcatT = (short*)alloc((size_t)T_ * HD_ * 2);
  short* gatT  = (short*)alloc((size_t)D_ * T_ * 2);

  const int RBg = N_ / 128, RBt = T_ / 128;            // 48, 24
  const size_t paccG1 = (size_t)H_ * RBg * 16384 * 2;
  const size_t paccT1 = (size_t)H_ * RBt * 16384 * 2;
  const size_t pzG1   = (size_t)H_ * RBg * 128 * 4;
  const size_t pzT1   = (size_t)H_ * RBt * 128 * 4;
  const size_t fcPg1  = (size_t)N_ * D_ * 4;
  const size_t fcPt1  = (size_t)T_ * D_ * 4;
  const size_t ctp1   = (size_t)N_ * D_ * 4;
  size_t rem = (ws_size > off + (1 << 20)) ? (ws_size - off - (1 << 20)) : 0;
  int Sg = 2, St = 2, Sf = 2, Sc = 2;
  size_t need16 = 16 * (paccG1 + pzG1) + 16 * (paccT1 + pzT1) + 4 * fcPg1 + 4 * fcPt1 + 4 * ctp1;
  size_t need8  = 8 * (paccG1 + pzG1) + 8 * (paccT1 + pzT1) + 4 * fcPg1 + 4 * fcPt1 + 4 * ctp1;
  size_t need4  = 4 * (paccG1 + pzG1) + 4 * (paccT1 + pzT1) + 2 * fcPg1 + 2 * fcPt1 + 2 * ctp1;
  if (rem >= need16)     { Sg = 16; St = 16; Sf = 4; Sc = 4; }
  else if (rem >= need8) { Sg = 8;  St = 8;  Sf = 4; Sc = 4; }
  else if (rem >= need4) { Sg = 4;  St = 4;  Sf = 2; Sc = 2; }
  _Float16* paccG = (_Float16*)alloc(Sg * paccG1);
  float* pzG   = (float*)alloc(Sg * pzG1);
  _Float16* paccT = (_Float16*)alloc(St * paccT1);
  float* pzT   = (float*)alloc(St * pzT1);
  float* fcPg  = (float*)alloc(Sf * fcPg1);
  float* fcPt  = (float*)alloc(Sf * fcPt1);
  float* ctextP = (float*)alloc(Sc * ctp1);

  // --- prep ---
  bits8_kernel<<<dim3(1536), dim3(256), 0, stream>>>(adj, t_adj, bitsG, bitsT,
                                                     N_ * N_ / 64, T_ * T_ / 64);
  cvt2_kernel<<<dim3((N_ + T_) * D_ / 1024), dim3(256), 0, stream>>>(
      x, xb, t_x, txb, N_ * D_ / 4, T_ * D_ / 4);
  tcvt2_kernel<<<dim3(4, 4, 8), dim3(32, 8), 0, stream>>>(
      Wg, WgT, Wt, WtT, D_, D_, (long)D_ * D_, (long)D_ * D_, 4);
  tcvt2_kernel<<<dim3(4, 16, 2), dim3(32, 8), 0, stream>>>(
      fcg_W, fcgT, fct_W, fctT, HD_, D_, 0, 0, 1);
  tcvt2_kernel<<<dim3(4, 4, 1), dim3(32, 8), 0, stream>>>(
      fus_W, fusT, fus_W, fusT, D_, D_, 0, 0, 1);
  tcvt2_kernel<<<dim3(N_ / 32, T_ / 32, 1), dim3(32, 8), 0, stream>>>(
      tfidf, tfidfT, tfidf, tfidfT, T_, N_, 0, 0, 1);
  fvec2_kernel<<<dim3(H_ * N_ / 256 + H_ * T_ / 256), dim3(256), 0, stream>>>(
      x, Wg, ag_src, ag_dst, eaG, ecG, ebG, edG, N_, H_ * N_ / 256,
      t_x, Wt, at_src, at_dst, eaT, ecT, ebT, edT, T_);

  // --- WhT = W^T x^T (G+T merged): fp16 out [H][128][n] ---
  gemm2_kernel<<<dim3(2, N_ / 128, 2 * H_), dim3(256), 0, stream>>>(
      WgT, xb, nullptr, WhTg, N_, (long)D_ * N_, 2, N_ / 128,
      WtT, txb, nullptr, WhTt, T_, (long)D_ * T_, 2, T_ / 128,
      D_, D_, D_, 0, (long)D_ * D_, 0, H_);

  // --- attention (G+T merged, 2-buffer pipeline, deeper k-split) ---
  attn2_kernel<<<dim3(RBg, H_, Sg + St), dim3(256), 0, stream>>>(
      WhTg, (const unsigned char*)bitsG, eaG, ecG, ebG, edG, paccG, pzG, N_, Sg, RBg,
      WhTt, (const unsigned char*)bitsT, eaT, ecT, ebT, edT, paccT, pzT, T_, St, RBt);
  combine2_kernel<<<dim3(RBg + RBt, H_), dim3(256), 0, stream>>>(
      paccG, pzG, hcatG, Sg, RBg, paccT, pzT, hcatT, St);

  // --- head-concat FC (G+T merged): fp32 k-split partials ---
  gemm2_kernel<<<dim3(N_ / 64, 1, 2 * Sf), dim3(256), 0, stream>>>(
      hcatG, fcgT, fcPg, nullptr, D_, (long)N_ * D_, N_ / 64, 1,
      hcatT, fctT, fcPt, nullptr, D_, (long)T_ * D_, T_ / 64, 1,
      HD_ / Sf, HD_, HD_, 3, (long)(HD_ / Sf), (long)(HD_ / Sf), Sf);
  reduce_kernel<<<dim3(T_ / 64), dim3(256), 0, stream>>>(
      fcPt, Sf, (long)T_ * D_, fct_b, gatT, T_);

  // --- c_text partials = tfidf^T @ gat_text ---
  gemm_kernel<<<dim3(N_ / 64, 1, Sc), dim3(256), 0, stream>>>(
      tfidfT, gatT, T_ / Sc, T_, T_, ctextP, nullptr, D_, 3,
      (long)(T_ / Sc), (long)(T_ / Sc), (long)N_ * D_);

  // --- gated fusion + final linear + relu ---
  fusion_kernel<<<dim3(N_ / 64), dim3(256), 0, stream>>>(
      fcPg, Sf, (long)N_ * D_, fcg_b, ctextP, Sc, (long)N_ * D_, fusT, fus_b, out);
}

// Round 17
// 337.054 us; speedup vs baseline: 1.1835x; 1.1835x over previous
//
#include <hip/hip_runtime.h>
#include <hip/hip_bf16.h>
#include <stdint.h>

#define N_  6144
#define T_  3072
#define D_  128
#define H_  4
#define HD_ 512

typedef float f32x4 __attribute__((ext_vector_type(4)));
typedef _Float16 f16x8 __attribute__((ext_vector_type(8)));
typedef _Float16 h16x4 __attribute__((ext_vector_type(4)));

#define GLL16(g, s) __builtin_amdgcn_global_load_lds( \
    (const __attribute__((address_space(1))) unsigned int*)(g), \
    (__attribute__((address_space(3))) unsigned int*)(s), 16, 0, 0)

static __device__ __forceinline__ short f2h(float f) {
  union { _Float16 h; short s; } u;
  u.h = (_Float16)f;
  return u.s;
}
static __device__ __forceinline__ unsigned pk2(float f) {
  union { _Float16 h[2]; unsigned u; } t;
  t.h[0] = (_Float16)f; t.h[1] = t.h[0];
  return t.u;
}
static __device__ __forceinline__ unsigned pkmul(unsigned a, unsigned b) {
  unsigned r;
  asm("v_pk_mul_f16 %0, %1, %2" : "=v"(r) : "v"(a), "v"(b));
  return r;
}
static __device__ __forceinline__ unsigned pkmax(unsigned a, unsigned b) {
  unsigned r;
  asm("v_pk_max_f16 %0, %1, %2" : "=v"(r) : "v"(a), "v"(b));
  return r;
}

// ---------------- adj + t_adj -> bitmasks, 8 words/wave-iter ----------------
__global__ __launch_bounds__(256) void bits8_kernel(const int* __restrict__ a0,
                                                    const int* __restrict__ a1,
                                                    unsigned long long* __restrict__ b0,
                                                    unsigned long long* __restrict__ b1,
                                                    int nw0, int nw1) {
  int lane = threadIdx.x & 63;
  int gw = (blockIdx.x * blockDim.x + threadIdx.x) >> 6;
  int nw = (gridDim.x * blockDim.x) >> 6;
  int total8 = (nw0 + nw1) >> 3;
  for (int g = gw; g < total8; g += nw) {
    int w = g * 8;
    const int* src; unsigned long long* dst; long wi;
    if (w < nw0) { src = a0; dst = b0; wi = w; }
    else         { src = a1; dst = b1; wi = w - nw0; }
    int v[8];
#pragma unroll
    for (int j = 0; j < 8; ++j) v[j] = src[(wi + j) * 64 + lane];
    unsigned long long bb[8];
#pragma unroll
    for (int j = 0; j < 8; ++j) bb[j] = __ballot(v[j] != 0);
    if (lane == 0) {
      ulonglong2 s01 = {bb[0], bb[1]}, s23 = {bb[2], bb[3]};
      ulonglong2 s45 = {bb[4], bb[5]}, s67 = {bb[6], bb[7]};
      *(ulonglong2*)(dst + wi + 0) = s01;
      *(ulonglong2*)(dst + wi + 2) = s23;
      *(ulonglong2*)(dst + wi + 4) = s45;
      *(ulonglong2*)(dst + wi + 6) = s67;
    }
  }
}

// ---------------- x + t_x fp32 -> fp16, one launch ----------------
__global__ __launch_bounds__(256) void cvt2_kernel(const float* __restrict__ in0,
                                                   short* __restrict__ out0,
                                                   const float* __restrict__ in1,
                                                   short* __restrict__ out1,
                                                   int c0, int c1) {
  int i = blockIdx.x * blockDim.x + threadIdx.x;
  const float* in; short* out; long ii;
  if (i < c0) { in = in0; out = out0; ii = i; }
  else if (i < c0 + c1) { in = in1; out = out1; ii = i - c0; }
  else return;
  float4 v = *(const float4*)(in + ii * 4);
  short4 o;
  o.x = f2h(v.x); o.y = f2h(v.y); o.z = f2h(v.z); o.w = f2h(v.w);
  *(short4*)(out + ii * 4) = o;
}

// ---------------- fp32 [R][C] -> fp16 [C][R], two jobs per launch ----------------
__global__ __launch_bounds__(256) void tcvt2_kernel(const float* __restrict__ in0,
                                                    short* __restrict__ out0,
                                                    const float* __restrict__ in1,
                                                    short* __restrict__ out1,
                                                    int R, int C, long sIn, long sOut,
                                                    int zsplit) {
  __shared__ float t[32][33];
  const float* in; short* out;
  int z = blockIdx.z;
  if (z < zsplit) { in = in0 + (long)z * sIn; out = out0 + (long)z * sOut; }
  else            { in = in1 + (long)(z - zsplit) * sIn; out = out1 + (long)(z - zsplit) * sOut; }
  int c0 = blockIdx.x * 32, r0 = blockIdx.y * 32;
  int tx = threadIdx.x, ty = threadIdx.y;
#pragma unroll
  for (int i = 0; i < 4; ++i)
    t[ty + 8 * i][tx] = in[(long)(r0 + ty + 8 * i) * C + c0 + tx];
  __syncthreads();
#pragma unroll
  for (int i = 0; i < 4; ++i)
    out[(long)(c0 + ty + 8 * i) * R + r0 + tx] = f2h(t[tx][ty + 8 * i]);
}

// ---------------- node factors, G+T merged: ea=e^fs, ec=e^.2fs (f32); eb,ed (fp16) ----
__global__ __launch_bounds__(256) void fvec2_kernel(const float* __restrict__ x0,
                                                    const float* __restrict__ W0,
                                                    const float* __restrict__ as0,
                                                    const float* __restrict__ ad0,
                                                    float* __restrict__ ea0, float* __restrict__ ec0,
                                                    short* __restrict__ eb0, short* __restrict__ ed0,
                                                    int n0, int xsplit,
                                                    const float* __restrict__ x1,
                                                    const float* __restrict__ W1,
                                                    const float* __restrict__ as1,
                                                    const float* __restrict__ ad1,
                                                    float* __restrict__ ea1, float* __restrict__ ec1,
                                                    short* __restrict__ eb1, short* __restrict__ ed1,
                                                    int n1) {
  const float *x, *W, *a_s, *a_d;
  float *ea, *ec; short *ebh, *edh; int n; long bx;
  if ((int)blockIdx.x < xsplit) { x=x0; W=W0; a_s=as0; a_d=ad0; ea=ea0; ec=ec0; ebh=eb0; edh=ed0; n=n0; bx=blockIdx.x; }
  else { x=x1; W=W1; a_s=as1; a_d=ad1; ea=ea1; ec=ec1; ebh=eb1; edh=ed1; n=n1; bx=blockIdx.x - xsplit; }
  __shared__ float usl[128], udl[128], asl[128], adl[128];
  long idx = bx * 256 + threadIdx.x;
  int h = (int)(idx / n), i = (int)(idx % n);
  int tid = threadIdx.x;
  if (tid < 128) {
    asl[tid] = a_s[h * D_ + tid];
    adl[tid] = a_d[h * D_ + tid];
  }
  __syncthreads();
  {
    int d = tid & 127;
    const float* wr = W + ((long)h * D_ + d) * D_;
    const float* av = (tid < 128) ? asl : adl;
    float s = 0.f;
#pragma unroll 8
    for (int e = 0; e < D_; ++e) s += wr[e] * av[e];
    if (tid < 128) usl[d] = s; else udl[d] = s;
  }
  __syncthreads();
  const float4* xr = (const float4*)(x + (long)i * D_);
  float s = 0.f, t = 0.f;
#pragma unroll 8
  for (int e4 = 0; e4 < 32; ++e4) {
    float4 xv = xr[e4];
    s += xv.x * usl[4 * e4] + xv.y * usl[4 * e4 + 1] + xv.z * usl[4 * e4 + 2] + xv.w * usl[4 * e4 + 3];
    t += xv.x * udl[4 * e4] + xv.y * udl[4 * e4 + 1] + xv.z * udl[4 * e4 + 2] + xv.w * udl[4 * e4 + 3];
  }
  const float L2E = 1.4426950408889634f;
  float fs = s * L2E, fd = t * L2E;
  ea[idx]  = exp2f(fs);
  ec[idx]  = exp2f(0.2f * fs);
  ebh[idx] = f2h(exp2f(fd));
  edh[idx] = f2h(exp2f(0.2f * fd));
}

// ---------------- GEMM core (3-buffer depth-2 GLL pipeline), used by both entries ----
#define GEMM_BODY(A, BT, K, lda, ldb, outF, outB, ldo, epi, sOutOff)            \
  {                                                                             \
    __shared__ __align__(16) short bs[3][4096];                                 \
    int tid = threadIdx.x, w = tid >> 6, l = tid & 63, lm = l & 15, lg = l >> 4;\
    int row0 = blockIdx.x * 64 + w * 16;                                        \
    int col0 = blockIdx.y * 128;                                                \
    const short* arow = (A) + (long)(row0 + lm) * (lda) + 8 * lg;               \
    const short* bsrc = (BT) + (long)(col0 + 16 * (2 * w) + lm) * (ldb) + 8 * lg;\
    f32x4 acc[8] = {};                                                          \
    int nt = (K) / 32;                                                          \
    f16x8 af = *(const f16x8*)(arow);                                           \
    GLL16(bsrc, &bs[0][(2 * w) * 512]);                                         \
    GLL16(bsrc + 16 * (ldb), &bs[0][(2 * w + 1) * 512]);                        \
    GLL16(bsrc + 32, &bs[1][(2 * w) * 512]);                                    \
    GLL16(bsrc + 32 + 16 * (ldb), &bs[1][(2 * w + 1) * 512]);                   \
    for (int kt = 0; kt < nt; ++kt) {                                           \
      int cur = kt % 3;                                                         \
      int kb = (kt + 1 < nt ? kt + 1 : kt) * 32;                                \
      f16x8 an = *(const f16x8*)(arow + kb);                                    \
      asm volatile("s_waitcnt vmcnt(3)" ::: "memory");                          \
      __builtin_amdgcn_sched_barrier(0);                                        \
      __builtin_amdgcn_s_barrier();                                             \
      __builtin_amdgcn_sched_barrier(0);                                        \
      _Pragma("unroll")                                                         \
      for (int f = 0; f < 8; ++f) {                                             \
        f16x8 bf = *(const f16x8*)(&bs[cur][f * 512 + l * 8]);                  \
        acc[f] = __builtin_amdgcn_mfma_f32_16x16x32_f16(af, bf, acc[f], 0, 0, 0);\
      }                                                                         \
      {                                                                         \
        int kg = (kt + 2 < nt ? kt + 2 : nt - 1) * 32;                          \
        int tb = (kt + 2) % 3;                                                  \
        GLL16(bsrc + kg, &bs[tb][(2 * w) * 512]);                               \
        GLL16(bsrc + kg + 16 * (ldb), &bs[tb][(2 * w + 1) * 512]);              \
      }                                                                         \
      __builtin_amdgcn_sched_barrier(0);                                        \
      af = an;                                                                  \
    }                                                                           \
    _Pragma("unroll")                                                           \
    for (int f = 0; f < 8; ++f) {                                               \
      int col = col0 + 16 * f + lm;                                             \
      _Pragma("unroll")                                                         \
      for (int r = 0; r < 4; ++r) {                                             \
        int row = row0 + 4 * lg + r;                                            \
        if ((epi) == 0) (outB)[(sOutOff) + (long)row * (ldo) + col] = f2h(acc[f][r]); \
        else            (outF)[(sOutOff) + (long)row * (ldo) + col] = acc[f][r];\
      }                                                                         \
    }                                                                           \
  }

// single-job entry (ctext)
__global__ __launch_bounds__(256) void gemm_kernel(const short* __restrict__ A,
                                                   const short* __restrict__ BT,
                                                   int K, int lda, int ldb,
                                                   float* __restrict__ outF, short* __restrict__ outB,
                                                   int ldo, int epi,
                                                   long sA, long sBT, long sOut) {
  int bz = blockIdx.z;
  const short* Ab = A + bz * sA;
  const short* Bb = BT + bz * sBT;
  long oOff = bz * sOut;
  GEMM_BODY(Ab, Bb, K, lda, ldb, outF, outB, ldo, epi, oOff)
}

// two-job entry (merged G/T)
__global__ __launch_bounds__(256) void gemm2_kernel(const short* __restrict__ A0,
                                                    const short* __restrict__ BT0,
                                                    float* __restrict__ oF0, short* __restrict__ oB0,
                                                    int ldo0, long sOut0, int xlim0, int ylim0,
                                                    const short* __restrict__ A1,
                                                    const short* __restrict__ BT1,
                                                    float* __restrict__ oF1, short* __restrict__ oB1,
                                                    int ldo1, long sOut1, int xlim1, int ylim1,
                                                    int K, int lda, int ldb, int epi,
                                                    long sA, long sBT, int zsplit) {
  int z = blockIdx.z;
  const short *A, *BT; float* outF; short* outB; int ldo; long sOut; int bz;
  if (z < zsplit) {
    if ((int)blockIdx.x >= xlim0 || (int)blockIdx.y >= ylim0) return;
    A = A0; BT = BT0; outF = oF0; outB = oB0; ldo = ldo0; sOut = sOut0; bz = z;
  } else {
    if ((int)blockIdx.x >= xlim1 || (int)blockIdx.y >= ylim1) return;
    A = A1; BT = BT1; outF = oF1; outB = oB1; ldo = ldo1; sOut = sOut1; bz = z - zsplit;
  }
  const short* Ab = A + bz * sA;
  const short* Bb = BT + bz * sBT;
  long oOff = bz * sOut;
  GEMM_BODY(Ab, Bb, K, lda, ldb, outF, outB, ldo, epi, oOff)
}

// ---------------- reduce fc partials: sum + bias + relu, fp16 transposed out ----
__global__ __launch_bounds__(256) void reduce_kernel(const float* __restrict__ P,
                                                     int S, long sP,
                                                     const float* __restrict__ bias,
                                                     short* __restrict__ outB,
                                                     int ldo) {
  __shared__ short sm[128][68];
  int tid = threadIdx.x;
  int r0 = blockIdx.x * 64;
#pragma unroll
  for (int k = 0; k < 8; ++k) {
    int e = tid * 4 + k * 1024;
    int row = e >> 7, col = e & 127;
    f32x4 v = {};
    for (int s = 0; s < S; ++s)
      v += *(const f32x4*)(P + (long)s * sP + (long)(r0 + row) * 128 + col);
    const float4 bv = *(const float4*)(bias + col);
    v[0] += bv.x; v[1] += bv.y; v[2] += bv.z; v[3] += bv.w;
#pragma unroll
    for (int q = 0; q < 4; ++q) v[q] = v[q] > 0.f ? v[q] : 0.f;
    sm[col + 0][row] = f2h(v[0]);
    sm[col + 1][row] = f2h(v[1]);
    sm[col + 2][row] = f2h(v[2]);
    sm[col + 3][row] = f2h(v[3]);
  }
  __syncthreads();
  int d = tid >> 1, seg = tid & 1;
  short* dst = outB + (long)d * ldo + r0 + seg * 32;
#pragma unroll
  for (int q = 0; q < 8; ++q) {
    short4 o;
    o.x = sm[d][seg * 32 + 4 * q + 0];
    o.y = sm[d][seg * 32 + 4 * q + 1];
    o.z = sm[d][seg * 32 + 4 * q + 2];
    o.w = sm[d][seg * 32 + 4 * q + 3];
    *(short4*)(dst + 4 * q) = o;
  }
}

// ---------------- merged masked-softmax attention (G+T), depth-3 prefetch ----
__global__ __launch_bounds__(256) void attn2_kernel(const short* __restrict__ WhT0,
                                                    const unsigned char* __restrict__ bits0,
                                                    const float* __restrict__ ea0A,
                                                    const float* __restrict__ ec0A,
                                                    const short* __restrict__ eb0A,
                                                    const short* __restrict__ ed0A,
                                                    _Float16* __restrict__ pacc0,
                                                    float* __restrict__ pz0,
                                                    int n0, int S0, int RB0,
                                                    const short* __restrict__ WhT1,
                                                    const unsigned char* __restrict__ bits1,
                                                    const float* __restrict__ ea1A,
                                                    const float* __restrict__ ec1A,
                                                    const short* __restrict__ eb1A,
                                                    const short* __restrict__ ed1A,
                                                    _Float16* __restrict__ pacc1,
                                                    float* __restrict__ pz1,
                                                    int n1, int S1, int RB1) {
  int z = blockIdx.z;
  const short* WhT; const unsigned char* bits;
  const float *eaA, *ecA; const short *ebA, *edA;
  _Float16* pacc; float* pz; int n, S, RB, sp;
  if (z < S0) {
    WhT = WhT0; bits = bits0; eaA = ea0A; ecA = ec0A; ebA = eb0A; edA = ed0A;
    pacc = pacc0; pz = pz0; n = n0; S = S0; RB = RB0; sp = z;
  } else {
    if ((int)blockIdx.x >= RB1) return;
    WhT = WhT1; bits = bits1; eaA = ea1A; ecA = ec1A; ebA = eb1A; edA = ed1A;
    pacc = pacc1; pz = pz1; n = n1; S = S1; RB = RB1; sp = z - S0;
  }
  int h = blockIdx.y;
  int klen = n / S, k0 = sp * klen;
  const short* whT = WhT + (long)h * D_ * n;
  const short* ebp = ebA + (long)h * n;
  const short* edp = edA + (long)h * n;
  __shared__ __align__(16) short bs[4][4096];
  int tid = threadIdx.x, w = tid >> 6, l = tid & 63, lm = l & 15, lg = l >> 4;
  int i0 = blockIdx.x * 128;
  int r0 = i0 + 32 * w + lm;
  int r1 = r0 + 16;
  unsigned ea0p = pk2(eaA[(long)h * n + r0]), ea1p = pk2(eaA[(long)h * n + r1]);
  unsigned ec0p = pk2(ecA[(long)h * n + r0]), ec1p = pk2(ecA[(long)h * n + r1]);
  const unsigned char* brow0 = bits + (long)r0 * (n >> 3);
  const unsigned char* brow1 = bits + (long)r1 * (n >> 3);
  const short* bsrc = whT + (long)(16 * (2 * w) + lm) * n + 8 * lg + k0;
  f32x4 acc0[8] = {}, acc1[8] = {};
  f32x4 az0 = {}, az1 = {};
  f16x8 ones;
#pragma unroll
  for (int j = 0; j < 8; ++j) ones[j] = (_Float16)1.0f;
  int nt = klen / 32;   // nt in {12,24,48,96}: %4==0, >=12
  unsigned eb0_[4], ed0_[4], eb1_[4], ed1_[4], eb2_[4], ed2_[4], eb3_[4], ed3_[4];
  unsigned m00, m10, m01, m11, m02, m12, m03, m13;
  // prologue: interleaved [streams(k), GLL(k)] for k=0,1,2 -> uniform vmcnt(18)
  *(uint4*)(eb0_) = *(const uint4*)(ebp + k0 + 8 * lg);
  *(uint4*)(ed0_) = *(const uint4*)(edp + k0 + 8 * lg);
  m00 = (*(const unsigned*)(brow0 + (k0 >> 3))) >> (8 * lg);
  m10 = (*(const unsigned*)(brow1 + (k0 >> 3))) >> (8 * lg);
  GLL16(bsrc, &bs[0][(2 * w) * 512]);
  GLL16(bsrc + 16 * n, &bs[0][(2 * w + 1) * 512]);
  __builtin_amdgcn_sched_barrier(0);
  *(uint4*)(eb1_) = *(const uint4*)(ebp + k0 + 32 + 8 * lg);
  *(uint4*)(ed1_) = *(const uint4*)(edp + k0 + 32 + 8 * lg);
  m01 = (*(const unsigned*)(brow0 + ((k0 + 32) >> 3))) >> (8 * lg);
  m11 = (*(const unsigned*)(brow1 + ((k0 + 32) >> 3))) >> (8 * lg);
  GLL16(bsrc + 32, &bs[1][(2 * w) * 512]);
  GLL16(bsrc + 32 + 16 * n, &bs[1][(2 * w + 1) * 512]);
  __builtin_amdgcn_sched_barrier(0);
  *(uint4*)(eb2_) = *(const uint4*)(ebp + k0 + 64 + 8 * lg);
  *(uint4*)(ed2_) = *(const uint4*)(edp + k0 + 64 + 8 * lg);
  m02 = (*(const unsigned*)(brow0 + ((k0 + 64) >> 3))) >> (8 * lg);
  m12 = (*(const unsigned*)(brow1 + ((k0 + 64) >> 3))) >> (8 * lg);
  GLL16(bsrc + 64, &bs[2][(2 * w) * 512]);
  GLL16(bsrc + 64 + 16 * n, &bs[2][(2 * w + 1) * 512]);
  __builtin_amdgcn_sched_barrier(0);

#define ATTN_STEP(KT, EBC, EDC, M0C, M1C, EBN, EDN, M0N, M1N)                   \
  {                                                                             \
    int cur = (KT) & 3;                                                         \
    int tgt = ((KT) + 3) & 3;                                                   \
    int kpre = ((KT) + 3 < nt ? (KT) + 3 : nt - 1) * 32;                        \
    *(uint4*)(EBN) = *(const uint4*)(ebp + k0 + kpre + 8 * lg);                 \
    *(uint4*)(EDN) = *(const uint4*)(edp + k0 + kpre + 8 * lg);                 \
    M0N = (*(const unsigned*)(brow0 + ((k0 + kpre) >> 3))) >> (8 * lg);         \
    M1N = (*(const unsigned*)(brow1 + ((k0 + kpre) >> 3))) >> (8 * lg);         \
    GLL16(bsrc + kpre, &bs[tgt][(2 * w) * 512]);                                \
    GLL16(bsrc + kpre + 16 * n, &bs[tgt][(2 * w + 1) * 512]);                   \
    __builtin_amdgcn_sched_barrier(0);                                          \
    union { f16x8 v; unsigned u[4]; } af0, af1;                                 \
    _Pragma("unroll")                                                           \
    for (int jj = 0; jj < 4; ++jj) {                                            \
      unsigned pm0 = pkmax(pkmul(ea0p, EBC[jj]), pkmul(ec0p, EDC[jj]));         \
      unsigned pm1 = pkmax(pkmul(ea1p, EBC[jj]), pkmul(ec1p, EDC[jj]));         \
      int ta = ((int)(M0C << (31 - 2 * jj))) >> 31;                             \
      int tb = ((int)(M0C << (30 - 2 * jj))) >> 31;                             \
      af0.u[jj] = pm0 & __builtin_amdgcn_perm((unsigned)tb, (unsigned)ta, 0x07060302u); \
      ta = ((int)(M1C << (31 - 2 * jj))) >> 31;                                 \
      tb = ((int)(M1C << (30 - 2 * jj))) >> 31;                                 \
      af1.u[jj] = pm1 & __builtin_amdgcn_perm((unsigned)tb, (unsigned)ta, 0x07060302u); \
    }                                                                           \
    asm volatile("s_waitcnt vmcnt(18)" ::: "memory");                           \
    __builtin_amdgcn_sched_barrier(0);                                          \
    __builtin_amdgcn_s_barrier();                                               \
    __builtin_amdgcn_sched_barrier(0);                                          \
    _Pragma("unroll")                                                           \
    for (int f = 0; f < 8; ++f) {                                               \
      f16x8 bf = *(const f16x8*)(&bs[cur][f * 512 + l * 8]);                    \
      acc0[f] = __builtin_amdgcn_mfma_f32_16x16x32_f16(af0.v, bf, acc0[f], 0, 0, 0); \
      acc1[f] = __builtin_amdgcn_mfma_f32_16x16x32_f16(af1.v, bf, acc1[f], 0, 0, 0); \
    }                                                                           \
    az0 = __builtin_amdgcn_mfma_f32_16x16x32_f16(af0.v, ones, az0, 0, 0, 0);    \
    az1 = __builtin_amdgcn_mfma_f32_16x16x32_f16(af1.v, ones, az1, 0, 0, 0);    \
    __builtin_amdgcn_sched_barrier(0);                                          \
  }

  for (int kt = 0; kt < nt; kt += 4) {
    ATTN_STEP(kt + 0, eb0_, ed0_, m00, m10, eb3_, ed3_, m03, m13);
    ATTN_STEP(kt + 1, eb1_, ed1_, m01, m11, eb0_, ed0_, m00, m10);
    ATTN_STEP(kt + 2, eb2_, ed2_, m02, m12, eb1_, ed1_, m01, m11);
    ATTN_STEP(kt + 3, eb3_, ed3_, m03, m13, eb2_, ed2_, m02, m12);
  }
#undef ATTN_STEP

  long base = (long)(h * RB + blockIdx.x) * S + sp;
  if (lm == 0) {
#pragma unroll
    for (int r = 0; r < 4; ++r) {
      pz[base * 128 + 32 * w + 4 * lg + r] = az0[r];
      pz[base * 128 + 32 * w + 16 + 4 * lg + r] = az1[r];
    }
  }
  long pb = base * 16384;
#pragma unroll
  for (int f = 0; f < 8; ++f)
#pragma unroll
    for (int r = 0; r < 4; ++r) {
      pacc[pb + (long)(32 * w + 4 * lg + r) * 128 + 16 * f + lm] = (_Float16)acc0[f][r];
      pacc[pb + (long)(32 * w + 16 + 4 * lg + r) * 128 + 16 * f + lm] = (_Float16)acc1[f][r];
    }
}

// ---------------- merged combine (G+T): /Z, elu, write fp16 head-concat ----
__global__ __launch_bounds__(256) void combine2_kernel(const _Float16* __restrict__ pacc0,
                                                       const float* __restrict__ pz0,
                                                       short* __restrict__ hcat0,
                                                       int S0, int RB0,
                                                       const _Float16* __restrict__ pacc1,
                                                       const float* __restrict__ pz1,
                                                       short* __restrict__ hcat1,
                                                       int S1) {
  const _Float16* pacc; const float* pz; short* hcat; int S, RB, rb;
  if ((int)blockIdx.x < RB0) { pacc = pacc0; pz = pz0; hcat = hcat0; S = S0; RB = RB0; rb = blockIdx.x; }
  else { pacc = pacc1; pz = pz1; hcat = hcat1; S = S1; RB = gridDim.x - RB0; rb = blockIdx.x - RB0; }
  int h = blockIdx.y;
  long base = (long)(h * RB + rb) * S;
  __shared__ float zl[128];
  int tid = threadIdx.x;
  if (tid < 128) {
    float zv = 0.f;
    for (int s = 0; s < S; ++s) zv += pz[(base + s) * 128 + tid];
    zl[tid] = 1.f / zv;
  }
  __syncthreads();
  int i0 = rb * 128;
#pragma unroll
  for (int k = 0; k < 16; ++k) {
    int e = tid * 4 + k * 1024;
    int row = e >> 7, col = e & 127;
    f32x4 v = {};
    for (int s = 0; s < S; ++s) {
      h16x4 hv = *(const h16x4*)(pacc + (base + s) * 16384 + e);
      v[0] += (float)hv[0]; v[1] += (float)hv[1];
      v[2] += (float)hv[2]; v[3] += (float)hv[3];
    }
    float iz = zl[row];
    short4 o;
    float t;
    t = v[0] * iz; o.x = f2h(t > 0.f ? t : __expf(t) - 1.f);
    t = v[1] * iz; o.y = f2h(t > 0.f ? t : __expf(t) - 1.f);
    t = v[2] * iz; o.z = f2h(t > 0.f ? t : __expf(t) - 1.f);
    t = v[3] * iz; o.w = f2h(t > 0.f ? t : __expf(t) - 1.f);
    *(short4*)(hcat + (long)(i0 + row) * HD_ + h * D_ + col) = o;
  }
}

// ---------------- gated fusion + final GEMM + relu ----
__global__ __launch_bounds__(256) void fusion_kernel(const float* __restrict__ fcPg,
                                                     int Sf, long sPg,
                                                     const float* __restrict__ fcg_b,
                                                     const float* __restrict__ ctextP,
                                                     int Sc, long sCt,
                                                     const short* __restrict__ fusT,
                                                     const float* __restrict__ fus_b,
                                                     float* __restrict__ out) {
  __shared__ __align__(16) short als[64 * 136];
  int tid = threadIdx.x;
  int r0 = blockIdx.x * 64;
#pragma unroll
  for (int it = 0; it < 8; ++it) {
    int e = it * 1024 + tid * 4;
    int r = e >> 7, c = e & 127;
    f32x4 cv = {};
    for (int s = 0; s < Sf; ++s)
      cv += *(const f32x4*)(fcPg + (long)s * sPg + (long)(r0 + r) * D_ + c);
    const float4 bv = *(const float4*)(fcg_b + c);
    cv[0] += bv.x; cv[1] += bv.y; cv[2] += bv.z; cv[3] += bv.w;
#pragma unroll
    for (int q = 0; q < 4; ++q) cv[q] = cv[q] > 0.f ? cv[q] : 0.f;
    f32x4 tv = {};
    for (int s = 0; s < Sc; ++s)
      tv += *(const f32x4*)(ctextP + (long)s * sCt + (long)(r0 + r) * D_ + c);
    short4 o;
    {
      float s0 = cv[0] + tv[0]; float z = 1.f / (1.f + __expf(-s0)); o.x = f2h(tv[0] + z * (cv[0] - tv[0]));
      s0 = cv[1] + tv[1]; z = 1.f / (1.f + __expf(-s0)); o.y = f2h(tv[1] + z * (cv[1] - tv[1]));
      s0 = cv[2] + tv[2]; z = 1.f / (1.f + __expf(-s0)); o.z = f2h(tv[2] + z * (cv[2] - tv[2]));
      s0 = cv[3] + tv[3]; z = 1.f / (1.f + __expf(-s0)); o.w = f2h(tv[3] + z * (cv[3] - tv[3]));
    }
    *(short4*)(als + (long)r * 136 + c) = o;
  }
  __syncthreads();
  int w = tid >> 6, l = tid & 63, lm = l & 15, lg = l >> 4;
  f32x4 acc[8] = {};
#pragma unroll
  for (int kt = 0; kt < 4; ++kt) {
    int kb = kt * 32;
    f16x8 af = *(const f16x8*)(als + (16 * w + lm) * 136 + kb + 8 * lg);
#pragma unroll
    for (int f = 0; f < 8; ++f) {
      f16x8 bf = *(const f16x8*)(fusT + (long)(16 * f + lm) * D_ + kb + 8 * lg);
      acc[f] = __builtin_amdgcn_mfma_f32_16x16x32_f16(af, bf, acc[f], 0, 0, 0);
    }
  }
#pragma unroll
  for (int f = 0; f < 8; ++f) {
    int col = 16 * f + lm;
#pragma unroll
    for (int r = 0; r < 4; ++r) {
      float v = acc[f][r] + fus_b[col];
      v = v > 0.f ? v : 0.f;
      out[(long)(r0 + 16 * w + 4 * lg + r) * D_ + col] = v;
    }
  }
}

extern "C" void kernel_launch(void* const* d_in, const int* in_sizes, int n_in,
                              void* d_out, int out_size, void* d_ws, size_t ws_size,
                              hipStream_t stream) {
  (void)in_sizes; (void)n_in; (void)out_size;
  const float* x      = (const float*)d_in[0];
  const int*   adj    = (const int*)d_in[1];
  const float* t_x    = (const float*)d_in[2];
  const int*   t_adj  = (const int*)d_in[3];
  const float* tfidf  = (const float*)d_in[4];
  const float* Wg     = (const float*)d_in[5];
  const float* ag_src = (const float*)d_in[6];
  const float* ag_dst = (const float*)d_in[7];
  const float* fcg_W  = (const float*)d_in[8];
  const float* fcg_b  = (const float*)d_in[9];
  const float* Wt     = (const float*)d_in[10];
  const float* at_src = (const float*)d_in[11];
  const float* at_dst = (const float*)d_in[12];
  const float* fct_W  = (const float*)d_in[13];
  const float* fct_b  = (const float*)d_in[14];
  const float* fus_W  = (const float*)d_in[15];
  const float* fus_b  = (const float*)d_in[16];
  float* out = (float*)d_out;

  char* ws = (char*)d_ws;
  size_t off = 0;
  auto alloc = [&](size_t bytes) -> char* {
    char* p = ws + off;
    off = (off + bytes + 255) & ~(size_t)255;
    return p;
  };
  unsigned long long* bitsG = (unsigned long long*)alloc((size_t)N_ * N_ / 8);
  unsigned long long* bitsT = (unsigned long long*)alloc((size_t)T_ * T_ / 8);
  short* xb     = (short*)alloc((size_t)N_ * D_ * 2);
  short* txb    = (short*)alloc((size_t)T_ * D_ * 2);
  short* WgT    = (short*)alloc((size_t)H_ * D_ * D_ * 2);
  short* WtT    = (short*)alloc((size_t)H_ * D_ * D_ * 2);
  short* fcgT   = (short*)alloc((size_t)HD_ * D_ * 2);
  short* fctT   = (short*)alloc((size_t)HD_ * D_ * 2);
  short* fusT   = (short*)alloc((size_t)D_ * D_ * 2);
  short* tfidfT = (short*)alloc((size_t)N_ * T_ * 2);
  short* WhTg   = (short*)alloc((size_t)H_ * D_ * N_ * 2);
  short* WhTt   = (short*)alloc((size_t)H_ * D_ * T_ * 2);
  float* eaG  = (float*)alloc((size_t)H_ * N_ * 4);
  float* ecG  = (float*)alloc((size_t)H_ * N_ * 4);
  short* ebG  = (short*)alloc((size_t)H_ * N_ * 2);
  short* edG  = (short*)alloc((size_t)H_ * N_ * 2);
  float* eaT  = (float*)alloc((size_t)H_ * T_ * 4);
  float* ecT  = (float*)alloc((size_t)H_ * T_ * 4);
  short* ebT  = (short*)alloc((size_t)H_ * T_ * 2);
  short* edT  = (short*)alloc((size_t)H_ * T_ * 2);
  short* hcatG = (short*)alloc((size_t)N_ * HD_ * 2);
  short* hcatT = (short*)alloc((size_t)T_ * HD_ * 2);
  short* gatT  = (short*)alloc((size_t)D_ * T_ * 2);

  const int RBg = N_ / 128, RBt = T_ / 128;            // 48, 24
  const size_t paccG1 = (size_t)H_ * RBg * 16384 * 2;
  const size_t paccT1 = (size_t)H_ * RBt * 16384 * 2;
  const size_t pzG1   = (size_t)H_ * RBg * 128 * 4;
  const size_t pzT1   = (size_t)H_ * RBt * 128 * 4;
  const size_t fcPg1  = (size_t)N_ * D_ * 4;
  const size_t fcPt1  = (size_t)T_ * D_ * 4;
  const size_t ctp1   = (size_t)N_ * D_ * 4;
  size_t rem = (ws_size > off + (1 << 20)) ? (ws_size - off - (1 << 20)) : 0;
  int Sg = 2, St = 2, Sf = 2, Sc = 2;
  size_t need8 = 8 * (paccG1 + pzG1) + 8 * (paccT1 + pzT1) + 4 * fcPg1 + 4 * fcPt1 + 4 * ctp1;
  size_t need4 = 4 * (paccG1 + pzG1) + 4 * (paccT1 + pzT1) + 2 * fcPg1 + 2 * fcPt1 + 2 * ctp1;
  if (rem >= need8)      { Sg = 8; St = 8; Sf = 4; Sc = 4; }
  else if (rem >= need4) { Sg = 4; St = 4; Sf = 2; Sc = 2; }
  _Float16* paccG = (_Float16*)alloc(Sg * paccG1);
  float* pzG   = (float*)alloc(Sg * pzG1);
  _Float16* paccT = (_Float16*)alloc(St * paccT1);
  float* pzT   = (float*)alloc(St * pzT1);
  float* fcPg  = (float*)alloc(Sf * fcPg1);
  float* fcPt  = (float*)alloc(Sf * fcPt1);
  float* ctextP = (float*)alloc(Sc * ctp1);

  // --- prep ---
  bits8_kernel<<<dim3(1536), dim3(256), 0, stream>>>(adj, t_adj, bitsG, bitsT,
                                                     N_ * N_ / 64, T_ * T_ / 64);
  cvt2_kernel<<<dim3((N_ + T_) * D_ / 1024), dim3(256), 0, stream>>>(
      x, xb, t_x, txb, N_ * D_ / 4, T_ * D_ / 4);
  tcvt2_kernel<<<dim3(4, 4, 8), dim3(32, 8), 0, stream>>>(
      Wg, WgT, Wt, WtT, D_, D_, (long)D_ * D_, (long)D_ * D_, 4);
  tcvt2_kernel<<<dim3(4, 16, 2), dim3(32, 8), 0, stream>>>(
      fcg_W, fcgT, fct_W, fctT, HD_, D_, 0, 0, 1);
  tcvt2_kernel<<<dim3(4, 4, 1), dim3(32, 8), 0, stream>>>(
      fus_W, fusT, fus_W, fusT, D_, D_, 0, 0, 1);
  tcvt2_kernel<<<dim3(N_ / 32, T_ / 32, 1), dim3(32, 8), 0, stream>>>(
      tfidf, tfidfT, tfidf, tfidfT, T_, N_, 0, 0, 1);
  fvec2_kernel<<<dim3(H_ * N_ / 256 + H_ * T_ / 256), dim3(256), 0, stream>>>(
      x, Wg, ag_src, ag_dst, eaG, ecG, ebG, edG, N_, H_ * N_ / 256,
      t_x, Wt, at_src, at_dst, eaT, ecT, ebT, edT, T_);

  // --- WhT = W^T x^T (G+T merged): fp16 out [H][128][n] ---
  gemm2_kernel<<<dim3(2, N_ / 128, 2 * H_), dim3(256), 0, stream>>>(
      WgT, xb, nullptr, WhTg, N_, (long)D_ * N_, 2, N_ / 128,
      WtT, txb, nullptr, WhTt, T_, (long)D_ * T_, 2, T_ / 128,
      D_, D_, D_, 0, (long)D_ * D_, 0, H_);

  // --- attention (G+T merged, depth-3 pipeline) ---
  attn2_kernel<<<dim3(RBg, H_, Sg + St), dim3(256), 0, stream>>>(
      WhTg, (const unsigned char*)bitsG, eaG, ecG, ebG, edG, paccG, pzG, N_, Sg, RBg,
      WhTt, (const unsigned char*)bitsT, eaT, ecT, ebT, edT, paccT, pzT, T_, St, RBt);
  combine2_kernel<<<dim3(RBg + RBt, H_), dim3(256), 0, stream>>>(
      paccG, pzG, hcatG, Sg, RBg, paccT, pzT, hcatT, St);

  // --- head-concat FC (G+T merged): fp32 k-split partials ---
  gemm2_kernel<<<dim3(N_ / 64, 1, 2 * Sf), dim3(256), 0, stream>>>(
      hcatG, fcgT, fcPg, nullptr, D_, (long)N_ * D_, N_ / 64, 1,
      hcatT, fctT, fcPt, nullptr, D_, (long)T_ * D_, T_ / 64, 1,
      HD_ / Sf, HD_, HD_, 3, (long)(HD_ / Sf), (long)(HD_ / Sf), Sf);
  reduce_kernel<<<dim3(T_ / 64), dim3(256), 0, stream>>>(
      fcPt, Sf, (long)T_ * D_, fct_b, gatT, T_);

  // --- c_text partials = tfidf^T @ gat_text ---
  gemm_kernel<<<dim3(N_ / 64, 1, Sc), dim3(256), 0, stream>>>(
      tfidfT, gatT, T_ / Sc, T_, T_, ctextP, nullptr, D_, 3,
      (long)(T_ / Sc), (long)(T_ / Sc), (long)N_ * D_);

  // --- gated fusion + final linear + relu ---
  fusion_kernel<<<dim3(N_ / 64), dim3(256), 0, stream>>>(
      fcPg, Sf, (long)N_ * D_, fcg_b, ctextP, Sc, (long)N_ * D_, fusT, fus_b, out);
}